// Round 1
// baseline (1883.667 us; speedup 1.0000x reference)
//
#include <hip/hip_runtime.h>

// Disable FP contraction globally: selection (IoU >= 0.5), argmax ties, and
// round(x) at 0.5 boundaries must be bit-identical to the numpy float32
// reference. All arithmetic below mirrors the reference's exact op order.
#pragma clang fp contract(off)

#define NPROP 2000
#define NGT   100
#define PCAP  66     // max positive ROIs
#define NCAP  134    // negative ROI slots
#define BIMG  4
#define MH    1024
#define MW    1024
#define NROI  200
#define MS    28

// out layout (floats): [0,3200) rois  [3200,4000) class ids
//                      [4000,7200) deltas  [7200,634400) masks
#define OUT_CLS   3200
#define OUT_DELTA 4000
#define OUT_MASK  7200

// ws layout:
//  ws[0]                       : mask dtype flag (0=int32, 1=uint8, 2=float32)
//  ws[8 .. 8+B*PCAP)           : per positive slot: gt index g if ok, else -1
//  byte offset 4096            : uchar flags[B*NPROP]   (bit0=pos, bit1=neg)
//  byte offset 16384           : short best[B*NPROP]    (first-argmax gt idx)
#define WS_META   8
#define WS_FLAGS  4096
#define WS_BEST   16384

// ---------------------------------------------------------------- kernel A
__global__ __launch_bounds__(256) void dtl_iou(
    const float* __restrict__ props,
    const int*   __restrict__ gcls,
    const float* __restrict__ gboxes,
    const unsigned int* __restrict__ gmasks_w,
    int* __restrict__ ws) {
  const int chunk = blockIdx.x;   // 0..7, 250 proposals each
  const int b     = blockIdx.y;   // image
  const int tid   = threadIdx.x;

  // mask dtype detection (one thread; 64 independent loads, overlapped)
  if (chunk == 0 && b == 0 && tid == 0) {
    int anyf = 0, anyb = 0;
#pragma unroll
    for (int k = 0; k < 64; ++k) {
      unsigned int v = gmasks_w[k];
      anyf |= (v == 0x3F800000u) ? 1 : 0;  // bilinear of float32 1.0
      anyb |= (v > 1u) ? 1 : 0;            // packed uint8 bytes
    }
    ws[0] = anyf ? 2 : (anyb ? 1 : 0);
  }

  __shared__ float s_gy1[NGT], s_gx1[NGT], s_gy2[NGT], s_gx2[NGT], s_ga[NGT];
  __shared__ unsigned char s_gok[NGT], s_gcr[NGT];
  if (tid < NGT) {
    const float* gp = gboxes + ((size_t)b * NGT + tid) * 4;
    float y1 = gp[0], x1 = gp[1], y2 = gp[2], x2 = gp[3];
    s_gy1[tid] = y1; s_gx1[tid] = x1; s_gy2[tid] = y2; s_gx2[tid] = x2;
    s_ga[tid]  = (y2 - y1) * (x2 - x1);
    bool valid = (y1 != 0.f) || (x1 != 0.f) || (y2 != 0.f) || (x2 != 0.f);
    int c = gcls[b * NGT + tid];
    s_gok[tid] = (valid && (c > 0)) ? 1 : 0;
    s_gcr[tid] = (valid && (c < 0)) ? 1 : 0;
  }
  __syncthreads();

  if (tid < 250) {
    int p = chunk * 250 + tid;
    const float* pb = props + ((size_t)b * NPROP + p) * 4;
    float py1 = pb[0], px1 = pb[1], py2 = pb[2], px2 = pb[3];
    bool pv = (py1 != 0.f) || (px1 != 0.f) || (py2 != 0.f) || (px2 != 0.f);
    float a1 = (py2 - py1) * (px2 - px1);

    float best = -1e30f; int bi = 0;
    float cmax = -1e30f;
    for (int g = 0; g < NGT; ++g) {
      float iy1 = fmaxf(py1, s_gy1[g]);
      float ix1 = fmaxf(px1, s_gx1[g]);
      float iy2 = fminf(py2, s_gy2[g]);
      float ix2 = fminf(px2, s_gx2[g]);
      float ih = fmaxf(iy2 - iy1, 0.f);
      float iw = fmaxf(ix2 - ix1, 0.f);
      float inter = ih * iw;
      float uni = (a1 + s_ga[g]) - inter;
      float iou = inter / (uni > 0.f ? uni : 1.0f);
      float ov = s_gok[g] ? iou : -1.0f;      // gt_ok-masked overlaps
      if (ov > best) { best = ov; bi = g; }   // first-occurrence argmax
      float cv = s_gcr[g] ? iou : -1.0f;      // crowd overlaps (raw iou)
      cmax = fmaxf(cmax, cv);
    }
    bool nocrowd = cmax < 0.001f;
    bool pos = pv && (best >= 0.5f);
    bool neg = pv && (best < 0.5f) && nocrowd;

    unsigned char* wf = ((unsigned char*)ws) + WS_FLAGS;
    short*         wb = (short*)(((char*)ws) + WS_BEST);
    wf[b * NPROP + p] = (unsigned char)((pos ? 1 : 0) | (neg ? 2 : 0));
    wb[b * NPROP + p] = (short)bi;
  }
}

// ---------------------------------------------------------------- kernel B
__global__ __launch_bounds__(256) void dtl_select(
    const float* __restrict__ props,
    const int*   __restrict__ gcls,
    const float* __restrict__ gboxes,
    float* __restrict__ out,
    int*   __restrict__ ws) {
  const int b = blockIdx.x;
  const int tid = threadIdx.x;

  __shared__ int s_pos[PCAP];
  __shared__ int s_neg[NCAP];
  __shared__ int s_np, s_nn;

  const unsigned char* wf = ((const unsigned char*)ws) + WS_FLAGS;
  const short*         wb = (const short*)(((const char*)ws) + WS_BEST);

  // Stable first-K compaction by wave 0 (ballot prefix-scan, 32 chunks)
  if (tid < 64) {
    const int lane = tid;
    const unsigned long long lt = (1ull << lane) - 1ull;
    int pc = 0, nc = 0;
    for (int c = 0; c < (NPROP + 63) / 64; ++c) {
      int i = c * 64 + lane;
      unsigned char f = (i < NPROP) ? wf[b * NPROP + i] : (unsigned char)0;
      bool ip = (f & 1) != 0;
      bool ng = (f & 2) != 0;
      unsigned long long pbm = __ballot(ip);
      unsigned long long nbm = __ballot(ng);
      if (ip) { int s = pc + __popcll(pbm & lt); if (s < PCAP) s_pos[s] = i; }
      if (ng) { int s = nc + __popcll(nbm & lt); if (s < NCAP) s_neg[s] = i; }
      pc += __popcll(pbm);
      nc += __popcll(nbm);
    }
    if (lane == 0) {
      int np = pc < PCAP ? pc : PCAP;                        // num_pos
      int nt = (int)((float)np / 0.33f) - np;                // trunc, f32 div
      int nn = nc < NCAP ? nc : NCAP;
      if (nn > nt) nn = nt;
      if (nn < 0) nn = 0;
      s_np = np; s_nn = nn;
    }
  }
  __syncthreads();

  if (tid < NROI) {
    const int slot = tid;
    float r0 = 0.f, r1 = 0.f, r2 = 0.f, r3 = 0.f;
    float d0 = 0.f, d1 = 0.f, d2 = 0.f, d3 = 0.f;
    float cls = 0.f;
    if (slot < PCAP) {
      int g = -1;
      if (slot < s_np) {
        int p = s_pos[slot];
        const float* pb = props + ((size_t)b * NPROP + p) * 4;
        r0 = pb[0]; r1 = pb[1]; r2 = pb[2]; r3 = pb[3];
        g = wb[b * NPROP + p];
        cls = (float)gcls[b * NGT + g];
        const float* gp = gboxes + ((size_t)b * NGT + g) * 4;
        float gy1 = gp[0], gx1 = gp[1], gy2 = gp[2], gx2 = gp[3];
        float h  = r2 - r0,  w  = r3 - r1;
        float gh = gy2 - gy1, gw = gx2 - gx1;
        float cy  = r0 + 0.5f * h,   cx  = r1 + 0.5f * w;
        float gcy = gy1 + 0.5f * gh, gcx = gx1 + 0.5f * gw;
        d0 = ((gcy - cy) / h) / 0.1f;
        d1 = ((gcx - cx) / w) / 0.1f;
        d2 = logf(gh / h) / 0.2f;
        d3 = logf(gw / w) / 0.2f;
      }
      ws[WS_META + b * PCAP + slot] = g;   // g if ok else -1, for mask kernel
    } else {
      int k = slot - PCAP;
      if (k < s_nn) {
        int p = s_neg[k];
        const float* pb = props + ((size_t)b * NPROP + p) * 4;
        r0 = pb[0]; r1 = pb[1]; r2 = pb[2]; r3 = pb[3];
      }
    }
    float* orow = out + ((size_t)b * NROI + slot) * 4;
    orow[0] = r0; orow[1] = r1; orow[2] = r2; orow[3] = r3;
    out[OUT_CLS + b * NROI + slot] = cls;
    float* drow = out + OUT_DELTA + ((size_t)b * NROI + slot) * 4;
    drow[0] = d0; drow[1] = d1; drow[2] = d2; drow[3] = d3;
  }
}

// ---------------------------------------------------------------- kernel C
__global__ __launch_bounds__(256) void dtl_mask(
    const void* __restrict__ gmasks,
    float* __restrict__ out,
    const int* __restrict__ ws) {
  const int slot = blockIdx.x;   // 0..199
  const int b    = blockIdx.y;
  const int tid  = threadIdx.x;

  float* dst = out + OUT_MASK + ((size_t)(b * NROI + slot)) * (MS * MS);
  const int g = (slot < PCAP) ? ws[WS_META + b * PCAP + slot] : -1;
  if (g < 0) {  // negative slot / empty positive slot -> zeros
    for (int px = tid; px < MS * MS; px += 256) dst[px] = 0.f;
    return;
  }
  const int flag = ws[0];
  const float* rb = out + ((size_t)b * NROI + slot) * 4;  // positive roi
  float y1 = rb[0], x1 = rb[1], y2 = rb[2], x2 = rb[3];

  for (int px = tid; px < MS * MS; px += 256) {
    int i = px / MS, j = px % MS;
    // ys = (y1 + ((y2-y1)*i)/27) * 1023   (exact reference op order)
    float ys = (y1 + ((y2 - y1) * (float)i) / 27.0f) * 1023.0f;
    float xs = (x1 + ((x2 - x1) * (float)j) / 27.0f) * 1023.0f;
    float y0f = fminf(fmaxf(floorf(ys), 0.f), 1023.f);
    float x0f = fminf(fmaxf(floorf(xs), 0.f), 1023.f);
    int y0i = (int)y0f, x0i = (int)x0f;
    int y1i = min(y0i + 1, MH - 1);
    int x1i = min(x0i + 1, MW - 1);
    float wy = ys - y0f;
    float wx = xs - x0f;

    auto at = [&](int yy, int xx) -> float {
      long long idx = (((long long)b * MH + yy) * MW + xx) * NGT + g;
      if (flag == 1) return (float)((const unsigned char*)gmasks)[idx];
      if (flag == 2) return ((const float*)gmasks)[idx];
      return (float)((const int*)gmasks)[idx];
    };
    float v = ((at(y0i, x0i) * (1.f - wy)) * (1.f - wx))
            + ((at(y0i, x1i) * (1.f - wy)) * wx)
            + ((at(y1i, x0i) * wy) * (1.f - wx))
            + ((at(y1i, x1i) * wy) * wx);
    dst[px] = rintf(v);   // round-half-even, matches jnp.round
  }
}

// ---------------------------------------------------------------- launcher
extern "C" void kernel_launch(void* const* d_in, const int* in_sizes, int n_in,
                              void* d_out, int out_size, void* d_ws, size_t ws_size,
                              hipStream_t stream) {
  const float* props  = (const float*)d_in[0];
  const int*   gcls   = (const int*)d_in[1];
  const float* gboxes = (const float*)d_in[2];
  const void*  gmasks = d_in[3];
  float* out = (float*)d_out;
  int*   ws  = (int*)d_ws;

  dtl_iou<<<dim3(8, BIMG), 256, 0, stream>>>(
      props, gcls, gboxes, (const unsigned int*)gmasks, ws);
  dtl_select<<<dim3(BIMG), 256, 0, stream>>>(props, gcls, gboxes, out, ws);
  dtl_mask<<<dim3(NROI, BIMG), 256, 0, stream>>>(gmasks, out, ws);
}